// Round 1
// baseline (459.261 us; speedup 1.0000x reference)
//
#include <hip/hip_runtime.h>
#include <hip/hip_bf16.h>
#include <cmath>

#define Bb 4
#define Tt 2048
#define Cc 1024
#define Hh 16
#define HDd 64

typedef __attribute__((ext_vector_type(8))) short short8;
typedef __attribute__((ext_vector_type(4))) float f32x4;

__device__ __forceinline__ unsigned short f32_bf16(float f) {
    unsigned u = __float_as_uint(f);
    u += 0x7FFF + ((u >> 16) & 1);
    return (unsigned short)(u >> 16);
}

// ---------------- fp32 -> bf16 convert ----------------
__global__ __launch_bounds__(256) void cvt_f32_bf16(const float* __restrict__ in,
                                                    unsigned short* __restrict__ out,
                                                    int n4) {
    int i = blockIdx.x * 256 + threadIdx.x;
    if (i < n4) {
        float4 v = ((const float4*)in)[i];
        ushort4 o;
        o.x = f32_bf16(v.x); o.y = f32_bf16(v.y);
        o.z = f32_bf16(v.z); o.w = f32_bf16(v.w);
        ((ushort4*)out)[i] = o;
    }
}

// ---------------- GEMM: out = A @ W^T + bias ----------------
// A: [M,K] bf16 row-major, W: [N,K] bf16 row-major (torch Linear convention)
// MODE 0: out bf16 head-major [B,H,T,HD]   (for q, k)
// MODE 1: out bf16 transposed [B,H,HD,T]   (for v)
// MODE 2: out fp32 row-major [M,N]         (final projection)
template <int MODE>
__global__ __launch_bounds__(256) void gemm_bt(const unsigned short* __restrict__ A,
                                               const unsigned short* __restrict__ W,
                                               const float* __restrict__ bias,
                                               void* __restrict__ out) {
    __shared__ unsigned short sA[128 * 40];  // +8 pad kills bank conflicts
    __shared__ unsigned short sB[128 * 40];

    const int tid  = threadIdx.x;
    const int bm0  = blockIdx.y * 128;
    const int bn0  = blockIdx.x * 128;
    const int wid  = tid >> 6;
    const int lane = tid & 63;
    const int quad = lane >> 4;
    const int lr   = lane & 15;
    const int wm   = (wid & 1) * 64;
    const int wn   = (wid >> 1) * 64;

    const int c0 = tid, c1 = tid + 256;
    const int r0 = c0 >> 2, k0 = (c0 & 3) * 8;
    const int r1 = c1 >> 2, k1 = (c1 & 3) * 8;

    f32x4 acc[4][4];
    f32x4 zero = {0.f, 0.f, 0.f, 0.f};
#pragma unroll
    for (int i = 0; i < 4; i++)
#pragma unroll
        for (int j = 0; j < 4; j++) acc[i][j] = zero;

    for (int kt = 0; kt < Cc / 32; ++kt) {
        const int kb = kt * 32;
        uint4 a0 = *(const uint4*)(A + (size_t)(bm0 + r0) * Cc + kb + k0);
        uint4 a1 = *(const uint4*)(A + (size_t)(bm0 + r1) * Cc + kb + k1);
        uint4 b0 = *(const uint4*)(W + (size_t)(bn0 + r0) * Cc + kb + k0);
        uint4 b1 = *(const uint4*)(W + (size_t)(bn0 + r1) * Cc + kb + k1);
        __syncthreads();
        *(uint4*)(sA + r0 * 40 + k0) = a0;
        *(uint4*)(sA + r1 * 40 + k1) = a1;
        *(uint4*)(sB + r0 * 40 + k0) = b0;
        *(uint4*)(sB + r1 * 40 + k1) = b1;
        __syncthreads();

        short8 af[4], bf[4];
#pragma unroll
        for (int i = 0; i < 4; i++)
            af[i] = *(const short8*)(sA + (wm + i * 16 + lr) * 40 + quad * 8);
#pragma unroll
        for (int j = 0; j < 4; j++)
            bf[j] = *(const short8*)(sB + (wn + j * 16 + lr) * 40 + quad * 8);
#pragma unroll
        for (int i = 0; i < 4; i++)
#pragma unroll
            for (int j = 0; j < 4; j++)
                acc[i][j] = __builtin_amdgcn_mfma_f32_16x16x32_bf16(af[i], bf[j], acc[i][j], 0, 0, 0);
    }

    // epilogue: C/D layout col = lane&15, row = quad*4 + reg
#pragma unroll
    for (int j = 0; j < 4; j++) {
        const int n = bn0 + wn + j * 16 + lr;
        const float bv = bias[n];
#pragma unroll
        for (int i = 0; i < 4; i++) {
#pragma unroll
            for (int r = 0; r < 4; r++) {
                const int m = bm0 + wm + i * 16 + quad * 4 + r;
                const float val = acc[i][j][r] + bv;
                if (MODE == 2) {
                    ((float*)out)[(size_t)m * Cc + n] = val;
                } else {
                    const int b = m >> 11, t = m & 2047;
                    const int h = n >> 6, hd = n & 63;
                    size_t idx;
                    if (MODE == 0)
                        idx = (((size_t)(b * Hh + h)) * Tt + t) * HDd + hd;
                    else
                        idx = (((size_t)(b * Hh + h)) * HDd + hd) * Tt + t;
                    ((unsigned short*)out)[idx] = f32_bf16(val);
                }
            }
        }
    }
}

// ---------------- flash attention ----------------
// q,k: [B,H,T,HD] bf16; vt: [B,H,HD,T] bf16; y: [B,T,C] bf16
__global__ __launch_bounds__(256) void attn(const unsigned short* __restrict__ q,
                                            const unsigned short* __restrict__ k,
                                            const unsigned short* __restrict__ vt,
                                            unsigned short* __restrict__ y) {
    __shared__ unsigned short sK[64 * 72];
    __shared__ unsigned short sV[64 * 72];          // [dim][key] (V transposed)
    __shared__ unsigned short sP[4 * 16 * 72];      // per-wave P tiles

    const int tid  = threadIdx.x;
    const int wid  = tid >> 6;
    const int lane = tid & 63;
    const int quad = lane >> 4;
    const int lr   = lane & 15;

    const int bh = blockIdx.y;                  // 0..63
    const int qt = gridDim.x - 1 - blockIdx.x;  // reversed: heavy tiles first
    const size_t headq = (size_t)bh * Tt * HDd;
    const int qb = qt * 64;

    // Q fragments (A-operand layout): row = qb + wid*16 + lr, k = quad*8 (+32)
    short8 qf0, qf1;
    {
        const unsigned short* qp = q + headq + (size_t)(qb + wid * 16 + lr) * HDd;
        qf0 = *(const short8*)(qp + quad * 8);
        qf1 = *(const short8*)(qp + 32 + quad * 8);
    }

    f32x4 o[4];
    f32x4 zero = {0.f, 0.f, 0.f, 0.f};
#pragma unroll
    for (int i = 0; i < 4; i++) o[i] = zero;
    float m_run[4], l_run[4];
#pragma unroll
    for (int r = 0; r < 4; r++) { m_run[r] = -INFINITY; l_run[r] = 0.f; }

    unsigned short* sPw = sP + wid * 16 * 72;
    const int ntiles = qt + 1;

    for (int kt = 0; kt < ntiles; ++kt) {
        __syncthreads();
        // stage K tile [64 keys][64 dims] and Vt tile [64 dims][64 keys]
        for (int c = tid; c < 512; c += 256) {
            const int row = c >> 3, c8 = (c & 7) * 8;
            *(uint4*)(sK + row * 72 + c8) =
                *(const uint4*)(k + headq + (size_t)(kt * 64 + row) * HDd + c8);
            *(uint4*)(sV + row * 72 + c8) =
                *(const uint4*)(vt + headq + (size_t)row * Tt + kt * 64 + c8);
        }
        __syncthreads();

        // S = Q @ K^T for 64 keys (4 col-frags of 16)
        f32x4 s[4];
#pragma unroll
        for (int nt = 0; nt < 4; nt++) {
            f32x4 a = zero;
            short8 b0 = *(const short8*)(sK + (nt * 16 + lr) * 72 + quad * 8);
            short8 b1 = *(const short8*)(sK + (nt * 16 + lr) * 72 + 32 + quad * 8);
            a = __builtin_amdgcn_mfma_f32_16x16x32_bf16(qf0, b0, a, 0, 0, 0);
            a = __builtin_amdgcn_mfma_f32_16x16x32_bf16(qf1, b1, a, 0, 0, 0);
            s[nt] = a;
        }

        // online softmax per q-row (row = quad*4 + r within this wave's strip)
#pragma unroll
        for (int r = 0; r < 4; r++) {
            const int gq = qb + wid * 16 + quad * 4 + r;
            float mx = -INFINITY;
#pragma unroll
            for (int nt = 0; nt < 4; nt++) {
                const int gk = kt * 64 + nt * 16 + lr;
                float val = s[nt][r] * 0.125f;
                val = (gk <= gq) ? val : -INFINITY;
                s[nt][r] = val;
                mx = fmaxf(mx, val);
            }
            mx = fmaxf(mx, __shfl_xor(mx, 1));
            mx = fmaxf(mx, __shfl_xor(mx, 2));
            mx = fmaxf(mx, __shfl_xor(mx, 4));
            mx = fmaxf(mx, __shfl_xor(mx, 8));

            const float mnew  = fmaxf(m_run[r], mx);
            const float alpha = __expf(m_run[r] - mnew);
            float rs = 0.f;
#pragma unroll
            for (int nt = 0; nt < 4; nt++) {
                const float p = __expf(s[nt][r] - mnew);
                s[nt][r] = p;
                rs += p;
            }
            rs += __shfl_xor(rs, 1);
            rs += __shfl_xor(rs, 2);
            rs += __shfl_xor(rs, 4);
            rs += __shfl_xor(rs, 8);
            l_run[r] = l_run[r] * alpha + rs;
            m_run[r] = mnew;
#pragma unroll
            for (int nt = 0; nt < 4; nt++) o[nt][r] *= alpha;
        }

        // P: C-layout -> LDS -> A-layout
#pragma unroll
        for (int nt = 0; nt < 4; nt++)
#pragma unroll
            for (int r = 0; r < 4; r++)
                sPw[(quad * 4 + r) * 72 + nt * 16 + lr] = f32_bf16(s[nt][r]);
        __syncthreads();

        short8 pa0 = *(const short8*)(sPw + lr * 72 + quad * 8);
        short8 pa1 = *(const short8*)(sPw + lr * 72 + 32 + quad * 8);
#pragma unroll
        for (int nt = 0; nt < 4; nt++) {
            short8 vb0 = *(const short8*)(sV + (nt * 16 + lr) * 72 + quad * 8);
            short8 vb1 = *(const short8*)(sV + (nt * 16 + lr) * 72 + 32 + quad * 8);
            o[nt] = __builtin_amdgcn_mfma_f32_16x16x32_bf16(pa0, vb0, o[nt], 0, 0, 0);
            o[nt] = __builtin_amdgcn_mfma_f32_16x16x32_bf16(pa1, vb1, o[nt], 0, 0, 0);
        }
    }

    // write O / l  ->  y [B,T,C]
    const int b = bh >> 4, h = bh & 15;
#pragma unroll
    for (int nt = 0; nt < 4; nt++) {
#pragma unroll
        for (int r = 0; r < 4; r++) {
            const int t   = qb + wid * 16 + quad * 4 + r;
            const int dim = nt * 16 + lr;
            const float val = o[nt][r] / l_run[r];
            y[((size_t)(b * Tt + t)) * Cc + h * HDd + dim] = f32_bf16(val);
        }
    }
}

// ---------------- launch ----------------
extern "C" void kernel_launch(void* const* d_in, const int* in_sizes, int n_in,
                              void* d_out, int out_size, void* d_ws, size_t ws_size,
                              hipStream_t stream) {
    const float* x  = (const float*)d_in[0];
    const float* Wk = (const float*)d_in[1];
    const float* bk = (const float*)d_in[2];
    const float* Wq = (const float*)d_in[3];
    const float* bq = (const float*)d_in[4];
    const float* Wv = (const float*)d_in[5];
    const float* bv = (const float*)d_in[6];
    const float* Wp = (const float*)d_in[7];
    const float* bp = (const float*)d_in[8];
    float* out = (float*)d_out;

    char* ws = (char*)d_ws;
    size_t off = 0;
    auto alloc = [&](size_t bytes) { char* p = ws + off; off += bytes; return p; };
    const size_t MK = (size_t)8192 * 1024;   // B*T*C elements
    const size_t NK = (size_t)1024 * 1024;   // C*C elements
    unsigned short* xb  = (unsigned short*)alloc(MK * 2);
    unsigned short* Wkb = (unsigned short*)alloc(NK * 2);
    unsigned short* Wqb = (unsigned short*)alloc(NK * 2);
    unsigned short* Wvb = (unsigned short*)alloc(NK * 2);
    unsigned short* Wpb = (unsigned short*)alloc(NK * 2);
    unsigned short* qh  = (unsigned short*)alloc(MK * 2);  // [B,H,T,HD]
    unsigned short* kh  = (unsigned short*)alloc(MK * 2);  // [B,H,T,HD]
    unsigned short* vth = (unsigned short*)alloc(MK * 2);  // [B,H,HD,T]
    unsigned short* ya  = (unsigned short*)alloc(MK * 2);  // [B,T,C]

    cvt_f32_bf16<<<(int)(MK / 4 + 255) / 256, 256, 0, stream>>>(x, xb, (int)(MK / 4));
    cvt_f32_bf16<<<(int)(NK / 4 + 255) / 256, 256, 0, stream>>>(Wk, Wkb, (int)(NK / 4));
    cvt_f32_bf16<<<(int)(NK / 4 + 255) / 256, 256, 0, stream>>>(Wq, Wqb, (int)(NK / 4));
    cvt_f32_bf16<<<(int)(NK / 4 + 255) / 256, 256, 0, stream>>>(Wv, Wvb, (int)(NK / 4));
    cvt_f32_bf16<<<(int)(NK / 4 + 255) / 256, 256, 0, stream>>>(Wp, Wpb, (int)(NK / 4));

    dim3 gg(8, 64);  // N/128, M/128
    gemm_bt<0><<<gg, 256, 0, stream>>>(xb, Wqb, bq, qh);
    gemm_bt<0><<<gg, 256, 0, stream>>>(xb, Wkb, bk, kh);
    gemm_bt<1><<<gg, 256, 0, stream>>>(xb, Wvb, bv, vth);

    attn<<<dim3(32, 64), 256, 0, stream>>>(qh, kh, vth, ya);

    gemm_bt<2><<<gg, 256, 0, stream>>>(ya, Wpb, bp, out);
}